// Round 5
// baseline (46.727 us; speedup 1.0000x reference)
//
#include <hip/hip_runtime.h>

// Static problem geometry (mirrors setup_inputs / _calc_step):
//   x: [B=8, N=64, P=256, D=256] f32, seq_len L=8192
//   step = (8192 - 256) / 63 = 125
//   out: [B, L, D] f32
#define B_    8
#define N_    64
#define P_    256
#define D_    256
#define L_    8192
#define STEP_ 125
#define ROWS_PER_WAVE 8

// True vector type (nontemporal builtins require a clang vector type).
typedef float v4f __attribute__((ext_vector_type(4)));

// One 64-lane wave owns 8 CONSECUTIVE output rows (b,l..l+7). Each lane owns
// 4 consecutive d's (16B/lane, 1KiB/wave per access). 8192 waves / 2048
// blocks: per-wave setup amortized 8x, sequential ~8KB read streams,
// compiler overlaps next row's loads with current row's reduce.
// Scatter inverted to gather: row l covered by n in
// [ceil((l-255)/125), floor(l/125)] clamped to [0,63] (0..3 nodes; rows
// l>8130 have ZERO contributors -> fused=0 -> out=beta, hence the cnt guard).
__global__ __launch_bounds__(256) void fusion_ln_kernel(
    const float* __restrict__ x,
    const float* __restrict__ gamma,
    const float* __restrict__ beta,
    float* __restrict__ out)
{
    const int wave = threadIdx.x >> 6;            // 0..3
    const int lane = threadIdx.x & 63;
    const int wid  = (blockIdx.x << 2) + wave;    // 0..8191
    const int row0 = wid * ROWS_PER_WAVE;         // 8-aligned; never straddles b
    const int b    = row0 >> 13;
    const int l0   = row0 & (L_ - 1);

    const int dbase = lane << 2;

    // Per-wave invariants: loaded/computed ONCE for 8 rows.
    const v4f g  = *reinterpret_cast<const v4f*>(gamma + dbase);
    const v4f be = *reinterpret_cast<const v4f*>(beta  + dbase);
    const float* xb = x + ((size_t)b * N_ * P_ * D_) + dbase;
    float*       ob = out + ((size_t)row0 * D_) + dbase;

    #pragma unroll
    for (int r = 0; r < ROWS_PER_WAVE; ++r) {
        const int l = l0 + r;
        int n_lo = (l >= P_) ? ((l - P_) / STEP_ + 1) : 0;
        int n_hi = l / STEP_;
        if (n_hi > N_ - 1) n_hi = N_ - 1;

        v4f acc = (v4f)(0.0f);
        const int cnt = n_hi - n_lo + 1;          // 0..3 (0 for l > 8130!)
        for (int n = n_lo; n <= n_hi; ++n) {
            const int p = l - n * STEP_;          // in [0, P)
            const v4f v = __builtin_nontemporal_load(
                reinterpret_cast<const v4f*>(xb + (size_t)(n * P_ + p) * D_));
            acc += v;
        }
        if (cnt > 0) acc *= (1.0f / (float)cnt);  // guard: cnt==0 tail rows

        // Fused butterfly: sum and sumsq in one 6-step reduce.
        float s  = acc.x + acc.y + acc.z + acc.w;
        float sq = acc.x * acc.x + acc.y * acc.y + acc.z * acc.z + acc.w * acc.w;
        #pragma unroll
        for (int m = 1; m < 64; m <<= 1) {
            s  += __shfl_xor(s,  m);
            sq += __shfl_xor(sq, m);
        }
        const float mu  = s  * (1.0f / (float)D_);
        float var = sq * (1.0f / (float)D_) - mu * mu;
        if (var < 0.f) var = 0.f;
        const float rstd = rsqrtf(var + 1e-5f);

        const v4f o = (acc - mu) * rstd * g + be;
        __builtin_nontemporal_store(o,
            reinterpret_cast<v4f*>(ob + (size_t)r * D_));
    }
}

extern "C" void kernel_launch(void* const* d_in, const int* in_sizes, int n_in,
                              void* d_out, int out_size, void* d_ws, size_t ws_size,
                              hipStream_t stream) {
    const float* x     = (const float*)d_in[0];
    const float* gamma = (const float*)d_in[1];
    const float* beta  = (const float*)d_in[2];
    // d_in[3] = seq_len (scalar 8192) -- geometry is compile-time static.
    float* out = (float*)d_out;

    const int rows   = B_ * L_;                          // 65536
    const int waves  = rows / ROWS_PER_WAVE;             // 8192
    const int blocks = waves / 4;                        // 2048
    fusion_ln_kernel<<<blocks, 256, 0, stream>>>(x, gamma, beta, out);
}

// Round 6
// 36.841 us; speedup vs baseline: 1.2683x; 1.2683x over previous
//
#include <hip/hip_runtime.h>

// Static problem geometry (mirrors setup_inputs / _calc_step):
//   x: [B=8, N=64, P=256, D=256] f32, seq_len L=8192
//   step = (8192 - 256) / 63 = 125
//   out: [B, L, D] f32
#define B_    8
#define N_    64
#define P_    256
#define D_    256
#define L_    8192
#define STEP_ 125

// True vector type (nontemporal builtins require a clang vector type).
typedef float v4f __attribute__((ext_vector_type(4)));

// R3 structure (best measured: 36.8us): one 64-lane wave per output row,
// 4 rows per 256-thread block, 16384 blocks. Lane owns 4 consecutive d's
// (16B/lane -> 1KiB per wave access). Scatter inverted to gather:
// row l covered by n in [ceil((l-255)/125), floor(l/125)] cap [0,63]
// (0..3 nodes; l>8130 -> 0 contributors -> fused=0 -> out=beta).
//
// NEW vs R3: XCD-aware chunked block swizzle (T1). Default dispatch
// round-robins consecutive blocks across 8 XCDs, so the per-stream 1KiB/row
// advance is torn into 32KiB-strided jumps per XCD. Chunked remap gives
// XCD k the contiguous block range [k*2048,(k+1)*2048) == batch k exactly:
// all its x reads fall in one contiguous 16MB slab (better L2/DRAM-page
// locality). nwg=16384 % 8 == 0 -> simple bijective form is valid.
__global__ __launch_bounds__(256) void fusion_ln_kernel(
    const float* __restrict__ x,
    const float* __restrict__ gamma,
    const float* __restrict__ beta,
    float* __restrict__ out)
{
    // Chunked XCD swizzle: hardware XCD = blockIdx.x % 8 (round-robin);
    // give that XCD a contiguous work chunk.
    const int sb   = (blockIdx.x & 7) * (16384 / 8) + (blockIdx.x >> 3);

    const int wave = threadIdx.x >> 6;          // 0..3 (4 rows per block)
    const int lane = threadIdx.x & 63;
    const int row  = (sb << 2) + wave;          // 0 .. B*L-1
    const int b    = row >> 13;                 // / L
    const int l    = row & (L_ - 1);

    int n_lo = (l >= P_) ? ((l - P_) / STEP_ + 1) : 0;
    int n_hi = l / STEP_;
    if (n_hi > N_ - 1) n_hi = N_ - 1;

    const int dbase = lane << 2;

    const v4f g  = *reinterpret_cast<const v4f*>(gamma + dbase);
    const v4f be = *reinterpret_cast<const v4f*>(beta  + dbase);

    v4f acc = (v4f)(0.0f);
    int cnt = 0;
    for (int n = n_lo; n <= n_hi; ++n) {
        const int p = l - n * STEP_;            // in [0, P)
        const v4f v = __builtin_nontemporal_load(
            reinterpret_cast<const v4f*>(
                x + (((size_t)(b * N_ + n) * P_ + p) * D_ + dbase)));
        acc += v;
        ++cnt;
    }
    if (cnt > 0) acc *= (1.0f / (float)cnt);    // cnt==0 tail: fused=0 -> beta

    // Fused butterfly: sum and sumsq in one 6-step reduce.
    float s  = acc.x + acc.y + acc.z + acc.w;
    float sq = acc.x * acc.x + acc.y * acc.y + acc.z * acc.z + acc.w * acc.w;
    #pragma unroll
    for (int m = 1; m < 64; m <<= 1) {
        s  += __shfl_xor(s,  m);
        sq += __shfl_xor(sq, m);
    }
    const float mu  = s  * (1.0f / (float)D_);
    float var = sq * (1.0f / (float)D_) - mu * mu;
    if (var < 0.f) var = 0.f;
    const float rstd = rsqrtf(var + 1e-5f);

    const v4f o = (acc - mu) * rstd * g + be;
    __builtin_nontemporal_store(o,
        reinterpret_cast<v4f*>(out + ((size_t)row * D_ + dbase)));
}

extern "C" void kernel_launch(void* const* d_in, const int* in_sizes, int n_in,
                              void* d_out, int out_size, void* d_ws, size_t ws_size,
                              hipStream_t stream) {
    const float* x     = (const float*)d_in[0];
    const float* gamma = (const float*)d_in[1];
    const float* beta  = (const float*)d_in[2];
    // d_in[3] = seq_len (scalar 8192) -- geometry is compile-time static.
    float* out = (float*)d_out;

    const int rows   = B_ * L_;       // 65536
    const int blocks = rows / 4;      // 16384 (divisible by 8 -> swizzle valid)
    fusion_ln_kernel<<<blocks, 256, 0, stream>>>(x, gamma, beta, out);
}